// Round 19
// baseline (41.594 us; speedup 1.0000x reference)
//
#include <hip/hip_runtime.h>

#define B_TOTAL 32768
#define NROWB   128            // rows per block
#define TILE    32             // rows per tile
#define NT      4              // tiles per block

typedef __attribute__((ext_vector_type(8)))  short    bf16x8;
typedef __attribute__((ext_vector_type(4)))  float    f32x4;
typedef __attribute__((ext_vector_type(4)))  unsigned u32x4;

// round-to-nearest-even fp32 -> bf16 (weights, one-time)
__device__ __forceinline__ unsigned rne1(float f) {
    unsigned u = __builtin_bit_cast(unsigned, f);
    return (u + 0x7FFFu + ((u >> 16) & 1u)) >> 16;
}
// HW packed fp32x2 -> bf16x2 (gfx950; no builtin)
__device__ __forceinline__ unsigned cvtpk(float lo, float hi) {
    unsigned r;
    asm("v_cvt_pk_bf16_f32 %0, %1, %2" : "=v"(r) : "v"(lo), "v"(hi));
    return r;
}
__device__ __forceinline__ float fsig(float v) {
    return __fdividef(1.0f, 1.0f + __expf(-v));
}
__device__ __forceinline__ float ftanh(float v) {
    return 1.0f - __fdividef(2.0f, 1.0f + __expf(2.0f * v));
}

// Weights -> COMPOSITE gate-interleaved fragments for mfma 16x16x32 (R8's
// verified layout).  Frag F = (s*2 + tau)*8 + ks, s = 8-hcol slice 0..15.
// B-col n16 = hl*4 + g  ->  D's j-index gives a lane all 4 GATES of one hcol.
__global__ void wconv_kernel(const float* __restrict__ w1, const float* __restrict__ w2,
                             const float* __restrict__ wf, const float* __restrict__ w3,
                             u32x4* __restrict__ out) {
    int T = blockIdx.x * 256 + threadIdx.x;   // 16384 threads
    int F = T >> 6, l = T & 63;
    int s = F >> 4, tau = (F >> 3) & 1, ks = F & 7;
    int n16 = l & 15;
    int g = n16 & 3, hl = n16 >> 2;
    const float* W = (g == 0) ? w1 : (g == 1) ? w2 : (g == 2) ? wf : w3;
    const float* src = W + (s * 8 + tau * 4 + hl) * 256 + ks * 32 + (l >> 4) * 8;
    f32x4 lo = *(const f32x4*)src;
    f32x4 hi = *(const f32x4*)(src + 4);
    u32x4 r;
    r[0] = rne1(lo[0]) | (rne1(lo[1]) << 16);
    r[1] = rne1(lo[2]) | (rne1(lo[3]) << 16);
    r[2] = rne1(hi[0]) | (rne1(hi[1]) << 16);
    r[3] = rne1(hi[2]) | (rne1(hi[3]) << 16);
    out[T] = r;
}

// R19: composite weights (64 VGPR/wave) + 512-thr blocks + 2 blocks/CU.
// Block: 8 waves = 64 cols (cg = bid&1), 128 rows as 4 tiles of 32.
// Wave: 8 hcols x 4 gates; 4 MFMA acc chains (2 mt x 2 tau).
// launch_bounds(512,4): 4 waves/SIMD cap (128 regs); est. use ~125.
// Staging: convert-once bf16, two-phase (ar = 8 VGPR), rotated slots.
__global__ __launch_bounds__(512, 4) void lstm_kernel(
    const float* __restrict__ x, const float* __restrict__ h, const float* __restrict__ c,
    const bf16x8* __restrict__ wfrag,
    const float* __restrict__ b1, const float* __restrict__ b2,
    const float* __restrict__ bfv, const float* __restrict__ b3,
    float* __restrict__ out)
{
    __shared__ __align__(16) char smem[2][16384];   // 32 KB bf16 A dbuf

    const int tid  = threadIdx.x;
    const int wave = tid >> 6;                // 0..7
    const int lane = tid & 63;
    const int rb   = lane & 15;               // batch row within 16
    const int c4   = lane >> 4;               // 0..3 = local hcol
    const int cg   = blockIdx.x & 1;
    const long row0 = (long)(blockIdx.x >> 1) * NROWB;
    const int s    = cg * 8 + wave;           // composite slice 0..15
    const int col0 = s * 8 + c4;              // tau=0 output col
    const int col1 = col0 + 4;                // tau=1 output col

    // ---- staging: thread owns 16 fp32 of row srow (two 8-fp32 phases) ----
    const int srow = tid >> 4;                // 0..31
    const int seg  = tid & 15;                // k-range seg*16..+16
    const int sks  = seg >> 1;                // ks of both phases
    const int smt  = srow >> 4;
    const int sr   = srow & 15;
    const int subA = (seg & 1) * 2;           // ksub of phase A (B = +1)
    const int offA = sks * 2048 + smt * 1024 + (((subA * 16 + sr) + sks) & 63) * 16;
    const int offB = sks * 2048 + smt * 1024 + ((((subA + 1) * 16 + sr) + sks) & 63) * 16;
    const float* const srcbase = (seg < 8) ? x : h;
    const int koff = (seg < 8) ? seg * 16 : seg * 16 - 128;

    f32x4 ar0, ar1;                           // 8 fp32 in flight (one phase)
    auto ISSUE = [&](int t, int ph) {
        const float* p = srcbase + (row0 + (long)t * TILE + srow) * 128 + koff + ph * 8;
        ar0 = *(const f32x4*)(p);
        ar1 = *(const f32x4*)(p + 4);
    };
    auto STORE = [&](int b, int ph) {
        u32x4 w;
        w[0] = cvtpk(ar0[0], ar0[1]);
        w[1] = cvtpk(ar0[2], ar0[3]);
        w[2] = cvtpk(ar1[0], ar1[1]);
        w[3] = cvtpk(ar1[2], ar1[3]);
        *(u32x4*)(smem[b & 1] + (ph ? offB : offA)) = w;
    };

    // ---- prologue: fill buf0 ----
    ISSUE(0, 0);

    bf16x8 wfr[2][8];                         // composite weights: 64 VGPRs
#pragma unroll
    for (int tau = 0; tau < 2; ++tau)
#pragma unroll
        for (int ks = 0; ks < 8; ++ks)
            wfr[tau][ks] = wfrag[(size_t)((s * 2 + tau) * 8 + ks) * 64 + lane];

    STORE(0, 0);
    ISSUE(0, 1);

    const f32x4 bias0 = (f32x4){ b1[col0], b2[col0], bfv[col0], b3[col0] };
    const f32x4 bias1 = (f32x4){ b1[col1], b2[col1], bfv[col1], b3[col1] };

    STORE(0, 1);

    float* out_h = out;
    float* out_c = out + (size_t)B_TOTAL * 128;

#pragma unroll 1
    for (int t = 0; t < NT; ++t) {
        asm volatile("s_waitcnt lgkmcnt(0)" ::: "memory");   // my ds_writes done
        __builtin_amdgcn_s_barrier();          // buf[t&1] complete block-wide
        __builtin_amdgcn_sched_barrier(0);

        const char* buf = smem[t & 1];
        const long gr0 = row0 + (long)t * TILE;

        if (t + 1 < NT) ISSUE(t + 1, 0);       // phase-A loads under MFMA

        f32x4 a00 = bias0, a01 = bias1;        // mt0: tau0, tau1
        f32x4 a10 = bias0, a11 = bias1;        // mt1

        __builtin_amdgcn_s_setprio(1);
#pragma unroll
        for (int ks = 0; ks < 8; ++ks) {
            const int rot = ((lane + ks) & 63) * 16;
            bf16x8 af0 = *(const bf16x8*)(buf + ks * 2048 + rot);
            bf16x8 af1 = *(const bf16x8*)(buf + ks * 2048 + 1024 + rot);
            a00 = __builtin_amdgcn_mfma_f32_16x16x32_bf16(wfr[0][ks], af0, a00, 0, 0, 0);
            a01 = __builtin_amdgcn_mfma_f32_16x16x32_bf16(wfr[1][ks], af0, a01, 0, 0, 0);
            a10 = __builtin_amdgcn_mfma_f32_16x16x32_bf16(wfr[0][ks], af1, a10, 0, 0, 0);
            a11 = __builtin_amdgcn_mfma_f32_16x16x32_bf16(wfr[1][ks], af1, a11, 0, 0, 0);
        }
        __builtin_amdgcn_s_setprio(0);

        if (t + 1 < NT) {
            STORE(t + 1, 0);                   // ar loaded a full MFMA loop ago
            ISSUE(t + 1, 1);                   // phase-B loads under epilogue
        }

        // epilogue: lane holds all 4 gates of (row, col0) and (row, col1)
        // for rows gr0+rb (mt0) and gr0+16+rb (mt1)
#pragma unroll
        for (int mt = 0; mt < 2; ++mt) {
            const long orow = (gr0 + mt * 16 + rb) * 128;
            const f32x4 acc0 = mt ? a10 : a00;
            const f32x4 acc1 = mt ? a11 : a01;
            const float cva = c[orow + col0];
            const float cvb = c[orow + col1];
            {
                const float G1 = fsig(acc0[0]);
                const float G2 = fsig(acc0[1]);
                const float GF = ftanh(acc0[2]);
                const float G3 = fsig(acc0[3]);
                const float nc = cva * G1 + G2 * GF;
                out_h[orow + col0] = ftanh(nc) * G3;
                out_c[orow + col0] = nc;
            }
            {
                const float G1 = fsig(acc1[0]);
                const float G2 = fsig(acc1[1]);
                const float GF = ftanh(acc1[2]);
                const float G3 = fsig(acc1[3]);
                const float nc = cvb * G1 + G2 * GF;
                out_h[orow + col1] = ftanh(nc) * G3;
                out_c[orow + col1] = nc;
            }
        }

        if (t + 1 < NT) STORE(t + 1, 1);       // before next lgkmcnt(0)+barrier
    }
}

extern "C" void kernel_launch(void* const* d_in, const int* in_sizes, int n_in,
                              void* d_out, int out_size, void* d_ws, size_t ws_size,
                              hipStream_t stream) {
    (void)in_sizes; (void)n_in; (void)out_size; (void)ws_size;
    const float* x  = (const float*)d_in[0];
    const float* h  = (const float*)d_in[1];
    const float* c  = (const float*)d_in[2];
    const float* W1 = (const float*)d_in[3];
    const float* b1 = (const float*)d_in[4];
    const float* W2 = (const float*)d_in[5];
    const float* b2 = (const float*)d_in[6];
    const float* Wf = (const float*)d_in[7];
    const float* bf = (const float*)d_in[8];
    const float* W3 = (const float*)d_in[9];
    const float* b3 = (const float*)d_in[10];

    wconv_kernel<<<64, 256, 0, stream>>>(W1, W2, Wf, W3, (u32x4*)d_ws);
    lstm_kernel<<<B_TOTAL / NROWB * 2, 512, 0, stream>>>(
        x, h, c, (const bf16x8*)d_ws, b1, b2, bf, b3, (float*)d_out);
}